// Round 6
// baseline (148.597 us; speedup 1.0000x reference)
//
#include <hip/hip_runtime.h>

// INRF fused:  out[b,ij,c] = sum_pq [ M2[ij,pq]*x[b,pq,c] - W2[ij,pq]*relu(x[b,pq,c] - S[b,pq,ij,c]) ]
//   S[b,pq,ij,f] = sum_k patch(x)[b,pq,k] * G[ij,k,f]   (3x3 SAME conv, K=144->pad 160)
//
// Round-6: R1/R3/R5 all pinned at ~45us despite wildly different occupancy/traffic ->
//   the invariant is the 2-phase stage->vmcnt(0)->barrier schedule (m233: caps MFMA util
//   at ~24%; our 10.3us MFMA floor / 0.24 = 43us = the invariant). This round ports
//   T3+T4 (counted vmcnt, never 0 in loop): 3-deep chunk pipeline, ALL loop VMEM via
//   global_load_lds (A + Xf + M + W = 5 issues/wave/chunk, uniform), per-phase
//   s_waitcnt vmcnt(10) -> barrier -> compute -> barrier -> stage chunk i+3.
//   M/W consumed from LDS as quad-broadcast ds_read_b128 (conflict-free).
//   256 blocks x 512 thr, 32 ij/block (4/wave), 32 tiles/block, LDS 120KB, 1 block/CU.

typedef __attribute__((ext_vector_type(8))) short bf16x8;
typedef __attribute__((ext_vector_type(4))) float f32x4;

__device__ inline unsigned short f2bf(float x) {
    unsigned u = __float_as_uint(x);
    u += 0x7FFFu + ((u >> 16) & 1u);          // round-to-nearest-even
    return (unsigned short)(u >> 16);
}
__device__ inline unsigned pack2(float a, float b) {
    return (unsigned)f2bf(a) | ((unsigned)f2bf(b) << 16);
}

__device__ inline void gld_lds16(const void* g, void* l) {
    __builtin_amdgcn_global_load_lds((const __attribute__((address_space(1))) void*)g,
                                     (__attribute__((address_space(3))) void*)l, 16, 0, 0);
}

// ---------------- Phase 1: A (im2col bf16 frags) + Xf (C-frag x) + Gf (bf16 B-frags) ----
// unit u = tid>>12:
//   u in [0,18): A tap = u>>1, h = u&1 -> uint4 at (tile, kk=tap>>1, quad=(tap&1)*2+h, m)
//   u == 18,19 : A zero-pad kk=4, quads 2,3
//   u in [20,24): Xf C-frag gather, one float4 per (tile, lane)
//   u in [24,28): zero out (16384 float4)
//   u in [28,108): Gf pack: one uint4 per (ij, kk, lane)
__global__ __launch_bounds__(256) void build_pre(const float* __restrict__ inp,
                                                 const float* __restrict__ G,
                                                 uint4* __restrict__ A,
                                                 float4* __restrict__ Xf,
                                                 uint4* __restrict__ Gf,
                                                 float4* __restrict__ outz) {
    const int tid = blockIdx.x * 256 + threadIdx.x;
    const int u = tid >> 12;
    if (u >= 28) {                            // G-pack: lane holds G[k=kk*32+quad*8+j][col]
        const int gidx = tid - 114688;        // 0..327679
        const int ijkk = gidx >> 6, l = gidx & 63;
        const int ij = ijkk / 5, kk = ijkk - ij * 5;
        const int quad = l >> 4, col = l & 15;
        const float* Gg = G + ij * 2304;
        float v[8];
#pragma unroll
        for (int j = 0; j < 8; ++j) {
            const int k = kk * 32 + quad * 8 + j;
            v[j] = (k < 144) ? Gg[k * 16 + col] : 0.f;
        }
        uint4 o;
        o.x = pack2(v[0], v[1]); o.y = pack2(v[2], v[3]);
        o.z = pack2(v[4], v[5]); o.w = pack2(v[6], v[7]);
        Gf[ij * 320 + kk * 64 + l] = o;
        return;
    }
    if (u >= 24) {
        outz[tid - 98304] = (float4){0.f, 0.f, 0.f, 0.f};
        return;
    }
    if (u >= 20) {
        const int idx = tid - 81920;          // 0..16383
        const int tile = idx >> 6, ll = idx & 63;
        const int rowb = tile * 16 + (ll >> 4) * 4;
        const int col = ll & 15;
        float4 v;
        v.x = inp[(rowb + 0) * 16 + col];
        v.y = inp[(rowb + 1) * 16 + col];
        v.z = inp[(rowb + 2) * 16 + col];
        v.w = inp[(rowb + 3) * 16 + col];
        Xf[idx] = v;
        return;
    }
    const int row = tid & 4095;
    const int tile = row >> 4, m = row & 15;
    if (u >= 18) {                            // zero-pad k=144..159 (kk=4, quads 2,3)
        const uint4 z = {0, 0, 0, 0};
        A[(tile * 5 + 4) * 64 + (u - 16) * 16 + m] = z;
        return;
    }
    const int tap = u >> 1, h = u & 1;
    const int dh = tap / 3, dw = tap - dh * 3;
    const int b = row >> 10, pq = row & 1023;
    const int p = pq >> 5, q = pq & 31;
    const int pp = p + dh - 1, qq = q + dw - 1;
    const int kk = tap >> 1, quad = (tap & 1) * 2 + h;
    uint4 o = {0, 0, 0, 0};
    if (((unsigned)pp < 32u) && ((unsigned)qq < 32u)) {
        const float4* s = (const float4*)(inp + b * 16384 + (pp * 32 + qq) * 16 + 8 * h);
        const float4 f0 = s[0], f1 = s[1];
        o.x = pack2(f0.x, f0.y); o.y = pack2(f0.z, f0.w);
        o.z = pack2(f1.x, f1.y); o.w = pack2(f1.z, f1.w);
    }
    A[(tile * 5 + kk) * 64 + quad * 16 + m] = o;
}

// ---------------- Phase 2: 256 blocks x 512 thr; 32 ij/block (4/wave), 32 tiles/block ---
__global__ __launch_bounds__(512, 1) void inrf_main(
    const float* __restrict__ M,     // (1024 ij, 1024 pq)
    const float* __restrict__ Wp,    // (1024 ij, 1024 pq)
    const uint4* __restrict__ Gf,    // bf16 B-frags: [ij*320 + kk*64 + lane]
    const uint4* __restrict__ Aw,    // swizzled bf16 patches, frag (tile,kk) at [..]*64+l
    const float4* __restrict__ Xf,   // x in C-frag layout
    float* __restrict__ out)         // (4,1024,16), pre-zeroed
{
    const int bid = blockIdx.x;
    const int ijblk = bid & 31;       // 32 ij-groups of 32 -> bid%8 = ijblk%8 (XCD co-loc)
    const int tgrp  = bid >> 5;       // 8 tile-groups of 32 tiles
    const int tile0 = tgrp * 32;
    const int bb    = tgrp >> 1;      // batch (32-tile groups never cross batches)

    const int t = threadIdx.x, l = t & 63, w = t >> 6;   // 8 waves
    const int quad = l >> 4;

    // 3-deep chunk pipeline; chunk = 4 tiles. 120 KB total.
    __shared__ __align__(16) uint4  Ab[3][4][5][64];    // 60 KB
    __shared__ __align__(16) float4 Xb[3][4][64];       // 12 KB
    __shared__ __align__(16) float  Mb[3][4][32][16];   // 24 KB
    __shared__ __align__(16) float  Wb[3][4][32][16];   // 24 KB

    // chunk staging: 40 issues (20 A + 4 Xf + 8 M + 8 W), exactly 5 per wave.
    // gld_lds dest = wave-uniform base + lane*16 (linear); all sources per-lane.
    auto stage = [&](int buf, int t0) {
#pragma unroll
        for (int r = 0; r < 5; ++r) {
            const int s = w * 5 + r;
            if (s < 20) {
                const int ct = s / 5, kk = s - ct * 5;
                gld_lds16(&Aw[((t0 + ct) * 5 + kk) * 64 + l], &Ab[buf][ct][kk][0]);
            } else if (s < 24) {
                const int ct = s - 20;
                gld_lds16(&Xf[(t0 + ct) * 64 + l], &Xb[buf][ct][0]);
            } else if (s < 32) {
                const int q = s - 24, ct = q >> 1, h = q & 1;
                const int ijg = ijblk * 32 + h * 16 + (l >> 2);
                const int pq0 = ((t0 + ct) & 63) * 16 + (l & 3) * 4;
                gld_lds16(&M[ijg * 1024 + pq0], &Mb[buf][ct][h * 16][0]);
            } else {
                const int q = s - 32, ct = q >> 1, h = q & 1;
                const int ijg = ijblk * 32 + h * 16 + (l >> 2);
                const int pq0 = ((t0 + ct) & 63) * 16 + (l & 3) * 4;
                gld_lds16(&Wp[ijg * 1024 + pq0], &Wb[buf][ct][h * 16][0]);
            }
        }
    };

    // B fragments first (oldest VMEM; retired by the first counted wait).
    const int ij0 = ijblk * 32 + w * 4;
    bf16x8 Bf[4][5];
#pragma unroll
    for (int ij = 0; ij < 4; ++ij)
#pragma unroll
        for (int kk = 0; kk < 5; ++kk)
            Bf[ij][kk] = __builtin_bit_cast(bf16x8, Gf[(ij0 + ij) * 320 + kk * 64 + l]);

    // prologue: stage chunks 0,1,2 (15 issues/wave outstanding)
    stage(0, tile0);
    stage(1, tile0 + 4);
    stage(2, tile0 + 8);

    float accv[4] = {0.f, 0.f, 0.f, 0.f};

#pragma unroll 1
    for (int ph = 0; ph < 8; ++ph) {
        // counted wait: chunks ph+1..min(ph+2,7) may stay in flight (5 issues each)
        if (ph < 6)      asm volatile("s_waitcnt vmcnt(10)" ::: "memory");
        else if (ph == 6) asm volatile("s_waitcnt vmcnt(5)" ::: "memory");
        else              asm volatile("s_waitcnt vmcnt(0)" ::: "memory");
        __builtin_amdgcn_s_barrier();      // chunk ph resident for all waves

        const int buf = ph % 3;
#pragma unroll
        for (int ct = 0; ct < 4; ++ct) {
            uint4 Af[5];
#pragma unroll
            for (int kk = 0; kk < 5; ++kk) Af[kk] = Ab[buf][ct][kk][l];   // ds_read_b128
            const float4 vr = Xb[buf][ct][l];

            f32x4 C[4];
#pragma unroll
            for (int jj = 0; jj < 4; ++jj) C[jj] = (f32x4){0.f, 0.f, 0.f, 0.f};
#pragma unroll
            for (int kk = 0; kk < 5; ++kk) {
                const bf16x8 a = __builtin_bit_cast(bf16x8, Af[kk]);
#pragma unroll
                for (int jj = 0; jj < 4; ++jj)
                    C[jj] = __builtin_amdgcn_mfma_f32_16x16x32_bf16(
                                a, Bf[jj][kk], C[jj], 0, 0, 0);
            }

            // fused epilogue: acc += M2*x - W2*relu(x - S); M/W from LDS (quad-broadcast)
#pragma unroll
            for (int jj = 0; jj < 4; ++jj) {
                const float4 w2 = *(const float4*)&Wb[buf][ct][w * 4 + jj][quad * 4];
                const float4 m2 = *(const float4*)&Mb[buf][ct][w * 4 + jj][quad * 4];
                float a0 = accv[jj];
                a0 += m2.x * vr.x - w2.x * fmaxf(vr.x - C[jj][0], 0.f);
                a0 += m2.y * vr.y - w2.y * fmaxf(vr.y - C[jj][1], 0.f);
                a0 += m2.z * vr.z - w2.z * fmaxf(vr.z - C[jj][2], 0.f);
                a0 += m2.w * vr.w - w2.w * fmaxf(vr.w - C[jj][3], 0.f);
                accv[jj] = a0;
            }
        }

        __builtin_amdgcn_s_barrier();      // all waves done reading buf before restage
        if (ph < 5) stage(buf, tile0 + (ph + 3) * 4);
    }

    // quad-reduce -> 16 cols per ij; 2 tile-group blocks per batch combine via atomicAdd
#pragma unroll
    for (int jj = 0; jj < 4; ++jj) {
        float v = accv[jj];
        v += __shfl_xor(v, 16);
        v += __shfl_xor(v, 32);
        if (l < 16) atomicAdd(&out[bb * 16384 + (ij0 + jj) * 16 + l], v);
    }
}

extern "C" void kernel_launch(void* const* d_in, const int* in_sizes, int n_in,
                              void* d_out, int out_size, void* d_ws, size_t ws_size,
                              hipStream_t stream) {
    const float* inp = (const float*)d_in[0];   // 65536
    const float* M   = (const float*)d_in[1];   // 1048576
    const float* Wp  = (const float*)d_in[2];   // 1048576
    const float* G   = (const float*)d_in[3];   // 2359296
    float* out = (float*)d_out;

    uint4*  A  = (uint4*)d_ws;                                    // 81920*16B  = 1.31 MB
    float4* Xf = (float4*)((char*)d_ws + 1310720);                // 16384*16B  = 256 KB
    uint4*  Gf = (uint4*)((char*)d_ws + 1572864);                 // 327680*16B = 5.24 MB

    build_pre<<<dim3(1728), dim3(256), 0, stream>>>(inp, G, A, Xf, Gf, (float4*)out);
    inrf_main<<<dim3(256), dim3(512), 0, stream>>>(M, Wp, Gf, A, Xf, out);
}

// Round 7
// 125.114 us; speedup vs baseline: 1.1877x; 1.1877x over previous
//
#include <hip/hip_runtime.h>

// INRF fused:  out[b,ij,c] = sum_pq [ M2[ij,pq]*x[b,pq,c] - W2[ij,pq]*relu(x[b,pq,c] - S[b,pq,ij,c]) ]
//   S[b,pq,ij,f] = sum_k patch(x)[b,pq,k] * G[ij,k,f]   (3x3 SAME conv, K=144->pad 160)
//
// Round-7: R0/R1/R3/R5 all pin at ~45us across occupancy/traffic/schedule knobs; R6's
//   all-LDS pipeline regressed (LDS pipe 1.7x oversubscribed). Per-CU pipe accounting
//   says VALU (~19us: ~13 fundamental epilogue + addressing) and MFMA issue (10.3us at
//   16x16x32) are the binders. This round switches MFMA shape to 32x32x16: HALF the
//   MFMA instructions for the same FLOPs (32K FLOP/instr), +15% rate (2382 vs 2075 TF),
//   half the issue slots -> more room for the VALU epilogue to overlap.
//   Layouts: A/B k-group = (l>>5)*8+j, row/col = l&31 (same convention as the verified
//   16x16 kernel); C/D col=lane&31, row=(reg&3)+8*(reg>>2)+4*(lane>>5) [m74/m101].
//   Structure = proven R0/R1 family: 256 blocks x 512 thr, 4 ij/block, M/W staged once
//   in LDS (32KB), A/x direct from L2, unroll-2 compiler pipelining, batch-disjoint
//   waves -> NO atomics, no out-zero pass.

typedef __attribute__((ext_vector_type(8))) short bf16x8;
typedef __attribute__((ext_vector_type(16))) float f32x16;

__device__ inline unsigned short f2bf(float x) {
    unsigned u = __float_as_uint(x);
    u += 0x7FFFu + ((u >> 16) & 1u);          // round-to-nearest-even
    return (unsigned short)(u >> 16);
}
__device__ inline unsigned pack2(float a, float b) {
    return (unsigned)f2bf(a) | ((unsigned)f2bf(b) << 16);
}

// ---------------- Phase 1: A32 (im2col bf16 32x32-frags) + Xf32 (C-frag x) + Gf32 ----
// A32[(T*10 + s)*64 + lane]: lane = h*32 + (row&31), h = k-half; s = tap (9 = zero pad).
//   content: 8 bf16 of patch(x)[row][k = s*16 + h*8 + j].
// Xf32[T*128 + lh*64 + g*16 + f]: float4 = x[T*32 + g*8 + lh*4 + 0..3][f]  (C-frag rows).
// Gf32[(ij2*10 + s)*64 + lane]: col=lane&31 -> (ij = ij2*2 + (col>>4), f = col&15),
//   h = lane>>5; 8 bf16 of G[ij][k = s*16 + h*8 + j][f].
// unit u = tid>>12: u<18 A-taps (row,tap,h); u 18-19 pad s=9; u 20-23 Xf; u>=24 Gf.
__global__ __launch_bounds__(256) void build_pre(const float* __restrict__ inp,
                                                 const float* __restrict__ G,
                                                 uint4* __restrict__ A,
                                                 float4* __restrict__ Xf,
                                                 uint4* __restrict__ Gf) {
    const int tid = blockIdx.x * 256 + threadIdx.x;
    const int u = tid >> 12;
    if (u >= 24) {                            // Gf pack: 327680 units
        const int gidx = tid - 98304;
        const int lane = gidx & 63;
        const int rem = gidx >> 6;            // ij2*10 + s
        const int ij2 = rem / 10, s = rem - ij2 * 10;
        const int col = lane & 31, h = lane >> 5;
        const int ij = ij2 * 2 + (col >> 4), f = col & 15;
        uint4 o = {0, 0, 0, 0};
        if (s < 9) {
            const float* Gg = G + ij * 2304 + s * 256 + h * 128 + f;
            o.x = pack2(Gg[0],  Gg[16]);
            o.y = pack2(Gg[32], Gg[48]);
            o.z = pack2(Gg[64], Gg[80]);
            o.w = pack2(Gg[96], Gg[112]);
        }
        Gf[gidx] = o;
        return;
    }
    if (u >= 20) {                            // Xf32: 16384 float4
        const int idx = tid - 81920;
        const int f = idx & 15, g = (idx >> 4) & 3, lh = (idx >> 6) & 1, T = idx >> 7;
        const int rb = T * 32 + g * 8 + lh * 4;
        float4 v;
        v.x = inp[(rb + 0) * 16 + f];
        v.y = inp[(rb + 1) * 16 + f];
        v.z = inp[(rb + 2) * 16 + f];
        v.w = inp[(rb + 3) * 16 + f];
        Xf[idx] = v;
        return;
    }
    if (u >= 18) {                            // zero-pad slice s=9: 8192 uint4
        const int flat = (u - 18) * 4096 + (tid & 4095);
        A[((flat >> 6) * 10 + 9) * 64 + (flat & 63)] = (uint4){0, 0, 0, 0};
        return;
    }
    // A taps: thread = (row, tap, h)
    const int row = tid & 4095;
    const int tap = u >> 1, h = u & 1;
    const int T = row >> 5;
    const int dh = tap / 3, dw = tap - dh * 3;
    const int b = row >> 10, pq = row & 1023;
    const int p = pq >> 5, q = pq & 31;
    const int pp = p + dh - 1, qq = q + dw - 1;
    uint4 o = {0, 0, 0, 0};
    if (((unsigned)pp < 32u) && ((unsigned)qq < 32u)) {
        const float4* s4 = (const float4*)(inp + b * 16384 + (pp * 32 + qq) * 16 + 8 * h);
        const float4 f0 = s4[0], f1 = s4[1];
        o.x = pack2(f0.x, f0.y); o.y = pack2(f0.z, f0.w);
        o.z = pack2(f1.x, f1.y); o.w = pack2(f1.z, f1.w);
    }
    A[(T * 10 + tap) * 64 + h * 32 + (row & 31)] = o;
}

// ---------------- Phase 2: 256 blocks x 512 thr; 4 ij/block; 32x32x16 MFMA ------------
// Wave w handles T = w*16 .. w*16+15 (one batch per wave: batch = w>>1).
__global__ __launch_bounds__(512, 1) void inrf_main(
    const float* __restrict__ M,     // (1024 ij, 1024 pq)
    const float* __restrict__ Wp,    // (1024 ij, 1024 pq)
    const uint4* __restrict__ Gf,    // bf16 B-frags (32x32 layout)
    const uint4* __restrict__ Aw,    // bf16 A-frags (32x32 layout)
    const float4* __restrict__ Xf,   // x in 32x32 C-frag layout
    float* __restrict__ out)         // (4,1024,16)
{
    const int bid = blockIdx.x;      // ij0 = bid*4
    const int t = threadIdx.x, l = t & 63, w = t >> 6;

    __shared__ __align__(16) float W2l[4096];
    __shared__ __align__(16) float M2l[4096];
    __shared__ float red[8][64];

    {   // stage M/W once: 4 contiguous ij rows each
        const float4* Wg = (const float4*)(Wp + bid * 4096);
        const float4* Mg = (const float4*)(M  + bid * 4096);
        float4* W4 = (float4*)W2l;
        float4* M4 = (float4*)M2l;
        W4[t] = Wg[t]; W4[t + 512] = Wg[t + 512];
        M4[t] = Mg[t]; M4[t + 512] = Mg[t + 512];
    }

    // B fragments: 2 ij-pairs x 10 k-slices (20 coalesced dwordx4)
    bf16x8 Bf[2][10];
#pragma unroll
    for (int p = 0; p < 2; ++p)
#pragma unroll
        for (int s = 0; s < 10; ++s)
            Bf[p][s] = __builtin_bit_cast(bf16x8, Gf[((bid * 2 + p) * 10 + s) * 64 + l]);

    __syncthreads();

    const int lh = l >> 5;           // k-half / row-half
    const int ijb = (l >> 4) & 1;    // which ij within the pair (from col = l&31)
    const int xcol = l & 15;         // f
    float acc0 = 0.f, acc1 = 0.f;

    const int T0 = w * 16;
#pragma unroll 2
    for (int i = 0; i < 16; ++i) {
        const int T = T0 + i;

        uint4 Af[10];
#pragma unroll
        for (int s = 0; s < 10; ++s) Af[s] = Aw[(T * 10 + s) * 64 + l];
        float4 xv[4];
#pragma unroll
        for (int g = 0; g < 4; ++g) xv[g] = Xf[(T * 2 + lh) * 64 + g * 16 + xcol];

        f32x16 C0 = {0.f}, C1 = {0.f};
#pragma unroll
        for (int s = 0; s < 10; ++s) {
            const bf16x8 a = __builtin_bit_cast(bf16x8, Af[s]);
            C0 = __builtin_amdgcn_mfma_f32_32x32x16_bf16(a, Bf[0][s], C0, 0, 0, 0);
            C1 = __builtin_amdgcn_mfma_f32_32x32x16_bf16(a, Bf[1][s], C1, 0, 0, 0);
        }

        // epilogue: acc += m2*x - w2*relu(x - S); rows (reg&3)+8*(reg>>2)+4*lh
        const int pqb = (T & 31) * 32 + lh * 4;
#pragma unroll
        for (int g = 0; g < 4; ++g) {
            const float4 xg = xv[g];
            {
                const float4 w2 = *(const float4*)&W2l[ijb * 1024 + pqb + g * 8];
                const float4 m2 = *(const float4*)&M2l[ijb * 1024 + pqb + g * 8];
                acc0 += m2.x * xg.x - w2.x * fmaxf(xg.x - C0[g * 4 + 0], 0.f);
                acc0 += m2.y * xg.y - w2.y * fmaxf(xg.y - C0[g * 4 + 1], 0.f);
                acc0 += m2.z * xg.z - w2.z * fmaxf(xg.z - C0[g * 4 + 2], 0.f);
                acc0 += m2.w * xg.w - w2.w * fmaxf(xg.w - C0[g * 4 + 3], 0.f);
            }
            {
                const float4 w2 = *(const float4*)&W2l[(2 + ijb) * 1024 + pqb + g * 8];
                const float4 m2 = *(const float4*)&M2l[(2 + ijb) * 1024 + pqb + g * 8];
                acc1 += m2.x * xg.x - w2.x * fmaxf(xg.x - C1[g * 4 + 0], 0.f);
                acc1 += m2.y * xg.y - w2.y * fmaxf(xg.y - C1[g * 4 + 1], 0.f);
                acc1 += m2.z * xg.z - w2.z * fmaxf(xg.z - C1[g * 4 + 2], 0.f);
                acc1 += m2.w * xg.w - w2.w * fmaxf(xg.w - C1[g * 4 + 3], 0.f);
            }
        }
    }

    // fold row-halves (lane l <-> l^32 share col), then cross-wave via red
    acc0 += __shfl_xor(acc0, 32);
    acc1 += __shfl_xor(acc1, 32);
    if (l < 32) { red[w][l] = acc0; red[w][32 + l] = acc1; }
    __syncthreads();

    if (t < 256) {
        const int ob = t >> 6, oij = (t >> 4) & 3, oc = t & 15;
        const int idx = (oij >> 1) * 32 + (oij & 1) * 16 + oc;
        out[ob * 16384 + (bid * 4 + oij) * 16 + oc] = red[ob * 2][idx] + red[ob * 2 + 1][idx];
    }
}

extern "C" void kernel_launch(void* const* d_in, const int* in_sizes, int n_in,
                              void* d_out, int out_size, void* d_ws, size_t ws_size,
                              hipStream_t stream) {
    const float* inp = (const float*)d_in[0];   // 65536
    const float* M   = (const float*)d_in[1];   // 1048576
    const float* Wp  = (const float*)d_in[2];   // 1048576
    const float* G   = (const float*)d_in[3];   // 2359296
    float* out = (float*)d_out;

    uint4*  A  = (uint4*)d_ws;                                    // 81920*16B  = 1.31 MB
    float4* Xf = (float4*)((char*)d_ws + 1310720);                // 16384*16B  = 256 KB
    uint4*  Gf = (uint4*)((char*)d_ws + 1572864);                 // 327680*16B = 5.24 MB

    build_pre<<<dim3(1664), dim3(256), 0, stream>>>(inp, G, A, Xf, Gf);
    inrf_main<<<dim3(256), dim3(512), 0, stream>>>(M, Wp, Gf, A, Xf, out);
}